// Round 2
// baseline (3750.467 us; speedup 1.0000x reference)
//
#include <hip/hip_runtime.h>
#include <stdint.h>
#include <math.h>
#include <limits.h>

// Batched autoregressive LSTM decode, B=32 S=48 V=32000 E=H=512.
// Round 2: logits GEMM via MFMA (split-bf16 emulated fp32, 3 passes),
// weights pre-packed into B-fragment order; final reduction fused into the
// logits kernel via last-block-done (device-scope atomics).

#define SEQ 48
#define BSZ 32
#define VOC 32000
#define EDIM 512
#define HDIM 512
#define GDIM 2048   // 4*H
#define KTOT 1024   // E + H
#define EOS_TOK (VOC - 2)
#define NBLK 250    // logits blocks (128 vocab each)

typedef __attribute__((ext_vector_type(8))) short bf16x8;
typedef __attribute__((ext_vector_type(4))) float f32x4;

__device__ __forceinline__ void threefry2x32(uint32_t k0, uint32_t k1,
                                             uint32_t x0, uint32_t x1,
                                             uint32_t& o0, uint32_t& o1)
{
  uint32_t ks2 = k0 ^ k1 ^ 0x1BD11BDAu;
  x0 += k0; x1 += k1;
#define TFR(r) x0 += x1; x1 = (x1 << (r)) | (x1 >> (32 - (r))); x1 ^= x0;
  TFR(13) TFR(15) TFR(26) TFR(6)
  x0 += k1; x1 += ks2 + 1u;
  TFR(17) TFR(29) TFR(16) TFR(24)
  x0 += ks2; x1 += k0 + 2u;
  TFR(13) TFR(15) TFR(26) TFR(6)
  x0 += k0; x1 += k1 + 3u;
  TFR(17) TFR(29) TFR(16) TFR(24)
  x0 += k1; x1 += ks2 + 4u;
  TFR(13) TFR(15) TFR(26) TFR(6)
  x0 += ks2; x1 += k0 + 5u;
#undef TFR
  o0 = x0; o1 = x1;
}

__device__ __forceinline__ uint32_t tf_bits(uint32_t k0, uint32_t k1, uint32_t m)
{
  // JAX partitionable threefry: 64-bit counter (hi=0, lo=m), draw = o0 ^ o1
  uint32_t o0, o1;
  threefry2x32(k0, k1, 0u, m, o0, o1);
  return o0 ^ o1;
}

__device__ __forceinline__ float gumbel_from_bits(uint32_t bits)
{
  uint32_t fb = (bits >> 9) | 0x3F800000u;
  float u = __uint_as_float(fb) - 1.0f;
  u = fmaxf(u, 1.1754943508222875e-38f);
  return -logf(-logf(u));
}

__device__ __forceinline__ float sigmoidf(float v) { return 1.0f / (1.0f + expf(-v)); }

__device__ __forceinline__ unsigned short f2bf(float f) {
  uint32_t u = __float_as_uint(f);
  uint32_t r = u + 0x7FFFu + ((u >> 16) & 1u);   // RNE
  return (unsigned short)(r >> 16);
}
__device__ __forceinline__ float bf2f(unsigned short h) {
  return __uint_as_float((uint32_t)h << 16);
}

__device__ __forceinline__ float dlf(const float* p) {
  return __hip_atomic_load(p, __ATOMIC_RELAXED, __HIP_MEMORY_SCOPE_AGENT);
}
__device__ __forceinline__ int dli(const int* p) {
  return __hip_atomic_load(p, __ATOMIC_RELAXED, __HIP_MEMORY_SCOPE_AGENT);
}
__device__ __forceinline__ void dsf(float* p, float v) {
  __hip_atomic_store(p, v, __ATOMIC_RELAXED, __HIP_MEMORY_SCOPE_AGENT);
}
__device__ __forceinline__ void dsi(int* p, int v) {
  __hip_atomic_store(p, v, __ATOMIC_RELAXED, __HIP_MEMORY_SCOPE_AGENT);
}

// ---------------------------------------------------------------- init
__global__ __launch_bounds__(256) void init_kernel(
    const float* __restrict__ encoded, float* __restrict__ h0,
    float* __restrict__ c, float* __restrict__ x,
    int* __restrict__ active, uint32_t* __restrict__ keys,
    int* __restrict__ counter)
{
  int i = blockIdx.x * 256 + threadIdx.x;
  if (i < BSZ * HDIM) { h0[i] = 0.0f; c[i] = 0.0f; x[i] = encoded[i]; }
  if (blockIdx.x == 0) {
    int t = threadIdx.x;
    if (t < BSZ) active[t] = 1;
    if (t < SEQ) {
      counter[t] = 0;
      uint32_t o0, o1;
      threefry2x32(0u, 42u, 0u, (uint32_t)t, o0, o1);
      keys[2 * t] = o0; keys[2 * t + 1] = o1;
    }
  }
}

// ---------------------------------------------------------------- transpose (cell weights)
// dst[(c + cOff)*dstLD + r] = src[r*C + c]
__global__ void transpose_kernel(const float* __restrict__ src, float* __restrict__ dst,
                                 int R, int C, int dstLD, int cOff)
{
  __shared__ float tile[32][33];
  int cb = blockIdx.x * 32, rb = blockIdx.y * 32;
  int tx = threadIdx.x, ty = threadIdx.y;
  for (int j = ty; j < 32; j += 8) {
    int r = rb + j, cc = cb + tx;
    if (r < R && cc < C) tile[j][tx] = src[(size_t)r * C + cc];
  }
  __syncthreads();
  for (int j = ty; j < 32; j += 8) {
    int r = rb + tx, cc = cb + j;
    if (r < R && cc < C) dst[(size_t)(cc + cOff) * dstLD + r] = tile[tx][j];
  }
}

// ---------------------------------------------------------------- weight frag pack
// Wo [32000][512] fp32 -> WP: frags [bid 250][ks 16][nt 8][plane 2][lane 64][8 bf16]
// plane 0 = bf16_rne(w), plane 1 = bf16_rne(w - hi)
__global__ __launch_bounds__(256) void wprep_kernel(
    const float* __restrict__ Wo, unsigned short* __restrict__ WP)
{
  int i4 = blockIdx.x * 256 + threadIdx.x;       // one float4 per thread
  if (i4 >= VOC * 128) return;
  int v  = i4 >> 7;
  int k  = (i4 & 127) * 4;
  const float4 wv = ((const float4*)Wo)[i4];
  int bid  = v >> 7;
  int nt   = (v >> 4) & 7;
  int lane = (v & 15) + (((k >> 3) & 3) << 4);
  int ks   = k >> 5;
  int e0   = k & 7;                               // 0 or 4
  size_t f = (((size_t)bid * 16 + ks) * 8 + nt) * 2;
  size_t base = f * 512 + (size_t)lane * 8 + e0;
  unsigned short a0 = f2bf(wv.x), a1 = f2bf(wv.y), a2 = f2bf(wv.z), a3 = f2bf(wv.w);
  *(ushort4*)(WP + base)       = make_ushort4(a0, a1, a2, a3);
  *(ushort4*)(WP + base + 512) = make_ushort4(f2bf(wv.x - bf2f(a0)), f2bf(wv.y - bf2f(a1)),
                                              f2bf(wv.z - bf2f(a2)), f2bf(wv.w - bf2f(a3)));
}

// ---------------------------------------------------------------- LSTM cell
// grid (32 jc, 8 bg), block 256; also emits h bf16 hi/lo planes for MFMA logits.
__global__ __launch_bounds__(256) void cell_kernel(
    const float* __restrict__ WT,   // [1024][2048] k-major combined Wi;Wh
    const float* __restrict__ bi, const float* __restrict__ bh,
    const float* __restrict__ x, const float* __restrict__ hin,
    float* __restrict__ hout, float* __restrict__ c,
    unsigned short* __restrict__ h1bf, unsigned short* __restrict__ h2bf)
{
  __shared__ float xh[KTOT * 4];
  __shared__ float red[4 * 64 * 4];
  __shared__ float gate[64 * 4];
  int t = threadIdx.x;
  int jc = blockIdx.x;
  int bg = blockIdx.y;
  int bbase = bg * 4;

  for (int i = 0; i < 16; ++i) {
    int idx = i * 256 + t;
    int b = idx >> 10, k = idx & 1023;
    float v = (k < EDIM) ? x[(bbase + b) * EDIM + k]
                         : hin[(bbase + b) * HDIM + (k - EDIM)];
    xh[k * 4 + b] = v;
  }
  __syncthreads();

  int gl = t & 63, kq = t >> 6;
  int type = gl >> 4, jj = gl & 15;
  int gcol = type * 512 + jc * 16 + jj;
  float acc0 = 0.f, acc1 = 0.f, acc2 = 0.f, acc3 = 0.f;
  const float* wp = WT + (size_t)(kq * 256) * GDIM + gcol;
  const float4* xp = (const float4*)xh + kq * 256;
#pragma unroll 8
  for (int k = 0; k < 256; ++k) {
    float w = wp[(size_t)k * GDIM];
    float4 h4 = xp[k];
    acc0 += w * h4.x; acc1 += w * h4.y; acc2 += w * h4.z; acc3 += w * h4.w;
  }
  ((float4*)red)[t] = make_float4(acc0, acc1, acc2, acc3);
  __syncthreads();

  if (t < 64) {
    float4 s0 = ((float4*)red)[t];
    float4 s1 = ((float4*)red)[64 + t];
    float4 s2 = ((float4*)red)[128 + t];
    float4 s3 = ((float4*)red)[192 + t];
    int ty2 = t >> 4, jj2 = t & 15;
    int gc2 = ty2 * 512 + jc * 16 + jj2;
    float bsum = bi[gc2] + bh[gc2];
    float4 g;
    g.x = s0.x + s1.x + s2.x + s3.x + bsum;
    g.y = s0.y + s1.y + s2.y + s3.y + bsum;
    g.z = s0.z + s1.z + s2.z + s3.z + bsum;
    g.w = s0.w + s1.w + s2.w + s3.w + bsum;
    ((float4*)gate)[t] = g;
  }
  __syncthreads();

  if (t < 64) {
    int b = t >> 4, jjf = t & 15;
    float ig = sigmoidf(gate[(0 * 16 + jjf) * 4 + b]);
    float fg = sigmoidf(gate[(1 * 16 + jjf) * 4 + b]);
    float gg = tanhf(  gate[(2 * 16 + jjf) * 4 + b]);
    float og = sigmoidf(gate[(3 * 16 + jjf) * 4 + b]);
    int ci = (bbase + b) * HDIM + jc * 16 + jjf;
    float cn = fg * c[ci] + ig * gg;
    c[ci] = cn;
    float hv = og * tanhf(cn);
    hout[ci] = hv;
    unsigned short hh = f2bf(hv);
    h1bf[ci] = hh;
    h2bf[ci] = f2bf(hv - bf2f(hh));
  }
}

// ---------------------------------------------------------------- logits (MFMA) + fused finalize
// grid 250 blocks x 128 vocab, 256 threads (4 waves x 32 vocab).
// logit = h1*W1 + h1*W2 + h2*W1 (bf16 splits), fp32 MFMA accumulate.
// Last block to finish does the global reduce + sampling + embed.
__global__ __launch_bounds__(256) void logits_kernel(
    const bf16x8* __restrict__ WP, const float* __restrict__ bo,
    const bf16x8* __restrict__ h1v, const bf16x8* __restrict__ h2v,
    const uint32_t* __restrict__ keys, int step,
    float* __restrict__ out,
    float* __restrict__ pmax, float* __restrict__ psum,
    float* __restrict__ pgv, int* __restrict__ pgi,
    int* __restrict__ counter,
    const float* __restrict__ emb, float* __restrict__ x,
    int* __restrict__ active, float* __restrict__ lse_s, int* __restrict__ act_s)
{
  __shared__ float cm[4][32], cs[4][32], cv[4][32];
  __shared__ int   cidx[4][32];
  __shared__ float fmx[8][32], fsx[8][32], fvx[8][32];
  __shared__ int   fix[8][32];
  __shared__ int   toks[32];
  __shared__ int   doneflag;

  const int t = threadIdx.x, bid = blockIdx.x;
  const int w = t >> 6, l = t & 63;
  const int lr = l & 15, lq = l >> 4;
  const int v0 = bid * 128;

  f32x4 a00 = {0.f, 0.f, 0.f, 0.f};
  f32x4 a01 = a00, a10 = a00, a11 = a00;

  // A-frag indices (units of bf16x8): h[row][k], row=mt*16+lr, k=ks*32+lq*8
  const int ab0 = lr * 64 + lq;
  const int ab1 = (16 + lr) * 64 + lq;
  // W-frag index: bid*16384 + ks*1024 + nt_g*128 + plane*64 + lane
  const int wb0 = bid * 16384 + (w * 2) * 128 + l;

#pragma unroll 2
  for (int ks = 0; ks < 16; ++ks) {
    bf16x8 x10 = h1v[ab0 + ks * 4];
    bf16x8 x11 = h1v[ab1 + ks * 4];
    bf16x8 x20 = h2v[ab0 + ks * 4];
    bf16x8 x21 = h2v[ab1 + ks * 4];
    const int wb = wb0 + ks * 1024;
    bf16x8 w10 = WP[wb];           // nt0 hi
    bf16x8 w20 = WP[wb + 64];      // nt0 lo
    bf16x8 w11 = WP[wb + 128];     // nt1 hi
    bf16x8 w21 = WP[wb + 192];     // nt1 lo
    a00 = __builtin_amdgcn_mfma_f32_16x16x32_bf16(x10, w10, a00, 0, 0, 0);
    a01 = __builtin_amdgcn_mfma_f32_16x16x32_bf16(x10, w11, a01, 0, 0, 0);
    a10 = __builtin_amdgcn_mfma_f32_16x16x32_bf16(x11, w10, a10, 0, 0, 0);
    a11 = __builtin_amdgcn_mfma_f32_16x16x32_bf16(x11, w11, a11, 0, 0, 0);
    a00 = __builtin_amdgcn_mfma_f32_16x16x32_bf16(x10, w20, a00, 0, 0, 0);
    a01 = __builtin_amdgcn_mfma_f32_16x16x32_bf16(x10, w21, a01, 0, 0, 0);
    a10 = __builtin_amdgcn_mfma_f32_16x16x32_bf16(x11, w20, a10, 0, 0, 0);
    a11 = __builtin_amdgcn_mfma_f32_16x16x32_bf16(x11, w21, a11, 0, 0, 0);
    a00 = __builtin_amdgcn_mfma_f32_16x16x32_bf16(x20, w10, a00, 0, 0, 0);
    a01 = __builtin_amdgcn_mfma_f32_16x16x32_bf16(x20, w11, a01, 0, 0, 0);
    a10 = __builtin_amdgcn_mfma_f32_16x16x32_bf16(x21, w10, a10, 0, 0, 0);
    a11 = __builtin_amdgcn_mfma_f32_16x16x32_bf16(x21, w11, a11, 0, 0, 0);
  }

  // D layout: col = lane&15 (vocab), row = (lane>>4)*4 + reg (batch)
  const int va = v0 + w * 32 + lr;
  const int vb = va + 16;
  const float boa = bo[va], bob = bo[vb];
  const uint32_t k0 = keys[2 * step], k1 = keys[2 * step + 1];

#pragma unroll
  for (int mt = 0; mt < 2; ++mt) {
    const f32x4 A0 = mt ? a10 : a00;
    const f32x4 A1 = mt ? a11 : a01;
#pragma unroll
    for (int reg = 0; reg < 4; ++reg) {
      const int b = mt * 16 + lq * 4 + reg;
      const float La = A0[reg] + boa;
      const float Lb = A1[reg] + bob;
      size_t obase = (size_t)b * (SEQ * VOC) + (size_t)step * VOC;
      out[obase + va] = La;
      out[obase + vb] = Lb;

      float mx = fmaxf(La, Lb);
      mx = fmaxf(mx, __shfl_xor(mx, 1, 64));
      mx = fmaxf(mx, __shfl_xor(mx, 2, 64));
      mx = fmaxf(mx, __shfl_xor(mx, 4, 64));
      mx = fmaxf(mx, __shfl_xor(mx, 8, 64));
      float se = expf(La - mx) + expf(Lb - mx);

      uint32_t ba = tf_bits(k0, k1, (uint32_t)(b * VOC + va));
      uint32_t bb = tf_bits(k0, k1, (uint32_t)(b * VOC + vb));
      float ga = La + gumbel_from_bits(ba);
      float gb = Lb + gumbel_from_bits(bb);
      float gvx; int gix;
      if (ga >= gb) { gvx = ga; gix = va; } else { gvx = gb; gix = vb; }
#pragma unroll
      for (int d = 1; d < 16; d <<= 1) {
        se += __shfl_xor(se, d, 64);
        float og = __shfl_xor(gvx, d, 64);
        int   oi = __shfl_xor(gix, d, 64);
        if (og > gvx || (og == gvx && oi < gix)) { gvx = og; gix = oi; }
      }
      if (lr == 0) {
        cm[w][b] = mx; cs[w][b] = se; cv[w][b] = gvx; cidx[w][b] = gix;
      }
    }
  }
  __syncthreads();

  if (t < 32) {
    const int b = t;
    float M = cm[0][b];
    M = fmaxf(M, cm[1][b]); M = fmaxf(M, cm[2][b]); M = fmaxf(M, cm[3][b]);
    float S = 0.f;
    float GV = -INFINITY; int GI = INT_MAX;
#pragma unroll
    for (int ww = 0; ww < 4; ++ww) {
      S += cs[ww][b] * expf(cm[ww][b] - M);
      if (cv[ww][b] > GV || (cv[ww][b] == GV && cidx[ww][b] < GI)) {
        GV = cv[ww][b]; GI = cidx[ww][b];
      }
    }
    dsf(pmax + bid * 32 + b, M);
    dsf(psum + bid * 32 + b, S);
    dsf(pgv  + bid * 32 + b, GV);
    dsi(pgi  + bid * 32 + b, GI);
    __threadfence();
  }
  __syncthreads();
  if (t == 0) {
    int old = __hip_atomic_fetch_add(counter + step, 1, __ATOMIC_ACQ_REL,
                                     __HIP_MEMORY_SCOPE_AGENT);
    doneflag = (old == NBLK - 1);
  }
  __syncthreads();

  if (doneflag) {
    __threadfence();
    const int b = t & 31, j = t >> 5;
    float M = -INFINITY, S = 0.f, GV = -INFINITY; int GI = INT_MAX;
    for (int i = j; i < NBLK; i += 8) {
      float m = dlf(pmax + i * 32 + b);
      float s = dlf(psum + i * 32 + b);
      float g = dlf(pgv  + i * 32 + b);
      int  gi = dli(pgi  + i * 32 + b);
      float mn = fmaxf(M, m);
      S = S * expf(M - mn) + s * expf(m - mn);
      M = mn;
      if (g > GV || (g == GV && gi < GI)) { GV = g; GI = gi; }
    }
    fmx[j][b] = M; fsx[j][b] = S; fvx[j][b] = GV; fix[j][b] = GI;
    __syncthreads();
    if (t < 32) {
      float M2 = fmx[0][t];
#pragma unroll
      for (int jj = 1; jj < 8; ++jj) M2 = fmaxf(M2, fmx[jj][t]);
      float S2 = 0.f; float GV2 = -INFINITY; int GI2 = INT_MAX;
#pragma unroll
      for (int jj = 0; jj < 8; ++jj) {
        S2 += fsx[jj][t] * expf(fmx[jj][t] - M2);
        if (fvx[jj][t] > GV2 || (fvx[jj][t] == GV2 && fix[jj][t] < GI2)) {
          GV2 = fvx[jj][t]; GI2 = fix[jj][t];
        }
      }
      lse_s[step * 32 + t] = M2 + logf(S2);
      act_s[step * 32 + t] = active[t];
      if (GI2 == EOS_TOK) active[t] = 0;
      toks[t] = GI2;
    }
    __syncthreads();
    for (int i = t; i < BSZ * 128; i += 256) {
      int row = i >> 7;
      ((float4*)x)[i] = ((const float4*)emb)[(size_t)toks[row] * 128 + (i & 127)];
    }
  }
}

// ---------------------------------------------------------------- epilogue
__global__ __launch_bounds__(256) void finish_kernel(
    float4* __restrict__ out4, const float* __restrict__ lse_s,
    const int* __restrict__ act_s)
{
  const int N4 = BSZ * SEQ * VOC / 4;
  for (int f = blockIdx.x * 256 + threadIdx.x; f < N4; f += gridDim.x * 256) {
    int row = f / (VOC / 4);
    int b = row / SEQ, s = row - b * SEQ;
    int idx = s * 32 + b;
    float4 v = out4[f];
    if (act_s[idx]) {
      float lsv = lse_s[idx];
      v.x -= lsv; v.y -= lsv; v.z -= lsv; v.w -= lsv;
    } else {
      v.x = 0.f; v.y = 0.f; v.z = 0.f; v.w = 0.f;
    }
    out4[f] = v;
  }
}

// ---------------------------------------------------------------- launch
extern "C" void kernel_launch(void* const* d_in, const int* in_sizes, int n_in,
                              void* d_out, int out_size, void* d_ws, size_t ws_size,
                              hipStream_t stream)
{
  (void)in_sizes; (void)n_in; (void)out_size; (void)ws_size;
  const float* encoded = (const float*)d_in[0];
  const float* emb     = (const float*)d_in[1];
  const float* Wi      = (const float*)d_in[2];
  const float* Wh      = (const float*)d_in[3];
  const float* bi      = (const float*)d_in[4];
  const float* bh      = (const float*)d_in[5];
  const float* Wo      = (const float*)d_in[6];
  const float* bo      = (const float*)d_in[7];
  float* out = (float*)d_out;

  char* W = (char*)d_ws;
  size_t off = 0;
  float* WT = (float*)(W + off);            off += (size_t)KTOT * GDIM * 4;        // 8 MB
  unsigned short* WP = (unsigned short*)(W + off); off += (size_t)VOC * 512 * 2 * 2; // 65.5 MB
  float* h0 = (float*)(W + off);            off += BSZ * HDIM * 4;
  float* h1 = (float*)(W + off);            off += BSZ * HDIM * 4;
  float* c  = (float*)(W + off);            off += BSZ * HDIM * 4;
  float* x  = (float*)(W + off);            off += BSZ * EDIM * 4;
  unsigned short* h1bf = (unsigned short*)(W + off); off += BSZ * HDIM * 2;
  unsigned short* h2bf = (unsigned short*)(W + off); off += BSZ * HDIM * 2;
  float* pmax = (float*)(W + off);          off += NBLK * 32 * 4;
  float* psum = (float*)(W + off);          off += NBLK * 32 * 4;
  float* pgv  = (float*)(W + off);          off += NBLK * 32 * 4;
  int*   pgi  = (int*)(W + off);            off += NBLK * 32 * 4;
  float* lse_s = (float*)(W + off);         off += SEQ * BSZ * 4;
  int*   act_s = (int*)(W + off);           off += SEQ * BSZ * 4;
  int*   active = (int*)(W + off);          off += 128;
  uint32_t* keys = (uint32_t*)(W + off);    off += SEQ * 2 * 4;
  int*   counter = (int*)(W + off);         off += SEQ * 4;

  init_kernel<<<dim3(64), dim3(256), 0, stream>>>(encoded, h0, c, x, active, keys, counter);
  transpose_kernel<<<dim3(16, 64), dim3(32, 8), 0, stream>>>(Wi, WT, GDIM, EDIM, GDIM, 0);
  transpose_kernel<<<dim3(16, 64), dim3(32, 8), 0, stream>>>(Wh, WT, GDIM, HDIM, GDIM, 512);
  wprep_kernel<<<dim3((VOC * 128 + 255) / 256), dim3(256), 0, stream>>>(Wo, WP);

  for (int s = 0; s < SEQ; ++s) {
    float* hin  = (s & 1) ? h1 : h0;
    float* hout = (s & 1) ? h0 : h1;
    cell_kernel<<<dim3(32, 8), dim3(256), 0, stream>>>(WT, bi, bh, x, hin, hout, c,
                                                       h1bf, h2bf);
    logits_kernel<<<dim3(NBLK), dim3(256), 0, stream>>>(
        (const bf16x8*)WP, bo, (const bf16x8*)h1bf, (const bf16x8*)h2bf,
        keys, s, out, pmax, psum, pgv, pgi, counter, emb, x, active, lse_s, act_s);
  }
  finish_kernel<<<dim3(2048), dim3(256), 0, stream>>>((float4*)out, lse_s, act_s);
}